// Round 4
// baseline (8638.643 us; speedup 1.0000x reference)
//
#include <hip/hip_runtime.h>
#include <hip/hip_bf16.h>

// Problem shape (fixed by setup_inputs)
#define BATCH 4
#define SEQ   4096
#define BS_TOK (BATCH*SEQ)   // 16384 rows
#define EMB   512
#define NH    8
#define HD    64
#define FF    2048
#define NL    6

typedef unsigned short u16;

__device__ __forceinline__ float bf2f(u16 u) {
    union { unsigned int i; float f; } x; x.i = ((unsigned int)u) << 16; return x.f;
}
__device__ __forceinline__ u16 f2bf(float f) {
    __hip_bfloat16 b = __float2bfloat16(f);
    return *(u16*)&b;
}

__device__ __forceinline__ float gelu_tanh(float x) {
    // jax.nn.gelu default (approximate=True)
    float x3 = x * x * x;
    return 0.5f * x * (1.f + tanhf(0.7978845608028654f * (x + 0.044715f * x3)));
}

// --- all overloads declared BEFORE any template that uses them
__device__ __forceinline__ void store_out(float* p, float v) { *p = v; }
__device__ __forceinline__ void store_out(u16* p, float v) { *p = f2bf(v); }

__device__ __forceinline__ void store8(float* p, const float* o) {
    *(float4*)p       = make_float4(o[0], o[1], o[2], o[3]);
    *(float4*)(p + 4) = make_float4(o[4], o[5], o[6], o[7]);
}
__device__ __forceinline__ void store8(u16* p, const float* o) {
    ushort4 a, b;
    a.x = f2bf(o[0]); a.y = f2bf(o[1]); a.z = f2bf(o[2]); a.w = f2bf(o[3]);
    b.x = f2bf(o[4]); b.y = f2bf(o[5]); b.z = f2bf(o[6]); b.w = f2bf(o[7]);
    *(ushort4*)p       = a;
    *(ushort4*)(p + 4) = b;
}

// ---------------------------------------------------------------------------
// Embedding lookup + sinusoidal positional embedding + padding mask
// grid = BS_TOK blocks, 128 threads, 4 elems/thread.  emb is f32.
// ---------------------------------------------------------------------------
__global__ __launch_bounds__(128) void embed_kernel(
        const int* __restrict__ tok, const float* __restrict__ emb,
        float* __restrict__ X, float* __restrict__ maskf) {
    int row = blockIdx.x;
    int t = threadIdx.x;
    int id = tok[row];
    if (t == 0) maskf[row] = (id > 0) ? 1.f : 0.f;
    int s = row & (SEQ - 1);
    int e0 = t * 4;
    float4 u = *(const float4*)(emb + (size_t)id * EMB + e0);
    float vals[4] = { u.x, u.y, u.z, u.w };
    float out[4];
#pragma unroll
    for (int j = 0; j < 4; ++j) {
        int ee = e0 + j;
        int i = ee >> 1;
        // div[i] = exp(2i * (-ln(10000)/512)) = exp(-i * ln(10000)/256)
        float div = expf(-0.035977892078031970f * (float)i);
        float ang = (float)s * div;
        float pe = (ee & 1) ? cosf(ang) : sinf(ang);
        out[j] = vals[j] + pe;
    }
    *(float4*)(X + (size_t)row * EMB + e0) = make_float4(out[0], out[1], out[2], out[3]);
}

// ---------------------------------------------------------------------------
// LayerNorm over E=512; one block (256 thr) per row; scale/bias f32.
// OUT = float (d_out / f32 buffers) or u16 (internal bf16)
// ---------------------------------------------------------------------------
template<typename OUT>
__global__ __launch_bounds__(256) void ln_kernel(
        const float* __restrict__ X, const float* __restrict__ sc,
        const float* __restrict__ bi, OUT* __restrict__ Y) {
    int row = blockIdx.x, t = threadIdx.x;
    const float* x = X + (size_t)row * EMB;
    float a = x[t], b = x[t + 256];
    float s = a + b, q = a * a + b * b;
#pragma unroll
    for (int off = 32; off; off >>= 1) {
        s += __shfl_xor(s, off);
        q += __shfl_xor(q, off);
    }
    __shared__ float ss[4], qq[4];
    int w = t >> 6;
    if ((t & 63) == 0) { ss[w] = s; qq[w] = q; }
    __syncthreads();
    s = ss[0] + ss[1] + ss[2] + ss[3];
    q = qq[0] + qq[1] + qq[2] + qq[3];
    float mu = s * (1.f / 512.f);
    float var = q * (1.f / 512.f) - mu * mu;
    float rstd = rsqrtf(var + 1e-6f);
    float y0 = (a - mu) * rstd * sc[t] + bi[t];
    float y1 = (b - mu) * rstd * sc[t + 256] + bi[t + 256];
    store_out(&Y[(size_t)row * EMB + t], y0);
    store_out(&Y[(size_t)row * EMB + t + 256], y1);
}

// ---------------------------------------------------------------------------
// Generic tiled GEMM: C[M,N] = epilogue(A[M,K](bf16 internal) * W[K,ldw](f32))
// 128x128 tile, BK=16, 256 threads, 8x8 per thread.
// OP: 0=none, 1=gelu, 2=relu+1e-3 (Performer phi)
// epilogue order: (+bias f32) -> OP -> (*rowscale[row]) -> (+residual f32)
// A ld = K; C ld = N; W ld = ldw (allows column-sliced W).
// M,N,K multiples of 128/128/16 (no bounds checks).
// ---------------------------------------------------------------------------
template<int OP, typename OUT>
__global__ __launch_bounds__(256) void gemm_kernel(
        const u16* __restrict__ A, const float* __restrict__ W,
        const float* __restrict__ bias, const float* __restrict__ rowscale,
        const float* __restrict__ residual, OUT* __restrict__ C,
        int M, int N, int K, int ldw) {
    __shared__ float As[16][132];   // k-major, padded
    __shared__ float Bs[16][132];
    int tid = threadIdx.x;
    int row0 = blockIdx.y * 128, col0 = blockIdx.x * 128;
    int tr = tid >> 4, tc = tid & 15;
    float acc[8][8];
#pragma unroll
    for (int i = 0; i < 8; ++i)
#pragma unroll
        for (int j = 0; j < 8; ++j) acc[i][j] = 0.f;

    for (int k0 = 0; k0 < K; k0 += 16) {
        // A tile: 128 rows x 16 k (bf16), transposed store into As[k][m]
#pragma unroll
        for (int u = 0; u < 2; ++u) {
            int vv = tid * 2 + u;           // 0..511 ushort4s
            int r = vv >> 2, c4 = (vv & 3) << 2;
            ushort4 a4 = *(const ushort4*)(A + (size_t)(row0 + r) * K + k0 + c4);
            As[c4 + 0][r] = bf2f(a4.x); As[c4 + 1][r] = bf2f(a4.y);
            As[c4 + 2][r] = bf2f(a4.z); As[c4 + 3][r] = bf2f(a4.w);
        }
        // W tile: 16 k x 128 cols (f32)
#pragma unroll
        for (int u = 0; u < 2; ++u) {
            int vv = tid * 2 + u;           // 0..511 float4s
            int r = vv >> 5, c = (vv & 31) << 2;
            float4 w4 = *(const float4*)(W + (size_t)(k0 + r) * ldw + col0 + c);
            Bs[r][c + 0] = w4.x; Bs[r][c + 1] = w4.y;
            Bs[r][c + 2] = w4.z; Bs[r][c + 3] = w4.w;
        }
        __syncthreads();
#pragma unroll
        for (int kk = 0; kk < 16; ++kk) {
            float a[8], bb[8];
            *(float4*)(a)      = *(const float4*)&As[kk][tr * 8];
            *(float4*)(a + 4)  = *(const float4*)&As[kk][tr * 8 + 4];
            *(float4*)(bb)     = *(const float4*)&Bs[kk][tc * 8];
            *(float4*)(bb + 4) = *(const float4*)&Bs[kk][tc * 8 + 4];
#pragma unroll
            for (int i = 0; i < 8; ++i)
#pragma unroll
                for (int j = 0; j < 8; ++j) acc[i][j] = fmaf(a[i], bb[j], acc[i][j]);
        }
        __syncthreads();
    }

    float bvals[8];
#pragma unroll
    for (int j = 0; j < 8; ++j) bvals[j] = bias ? bias[col0 + tc * 8 + j] : 0.f;
#pragma unroll
    for (int i = 0; i < 8; ++i) {
        int r = row0 + tr * 8 + i;
        float rsv = rowscale ? rowscale[r] : 1.f;
        float o[8];
#pragma unroll
        for (int j = 0; j < 8; ++j) {
            float val = acc[i][j] + bvals[j];
            if (OP == 1) val = gelu_tanh(val);
            if (OP == 2) val = fmaxf(val, 0.f) + 1e-3f;
            o[j] = val * rsv;
        }
        size_t cbase = (size_t)r * N + col0 + tc * 8;
        if (residual) {
            float4 r0 = *(const float4*)(residual + cbase);
            float4 r1 = *(const float4*)(residual + cbase + 4);
            o[0] += r0.x; o[1] += r0.y; o[2] += r0.z; o[3] += r0.w;
            o[4] += r1.x; o[5] += r1.y; o[6] += r1.z; o[7] += r1.w;
        }
        store8(&C[cbase], o);
    }
}

// ---------------------------------------------------------------------------
// kv[b,h,m,d] = sum_s phi_k[b,s,h,m] * v[b,s,h,d];  z[b,h,m] = sum_s phi_k
// grid = (B*H, SEQ/256); 256 threads; 4x4 accum/thread; atomics into zeroed buf
// PK, V are internal bf16.
// ---------------------------------------------------------------------------
__global__ __launch_bounds__(256) void kv_reduce(
        const u16* __restrict__ PK, const u16* __restrict__ V,
        float* __restrict__ KV, float* __restrict__ Z) {
    int bh = blockIdx.x;
    int b = bh >> 3, hh = bh & 7;
    int c = blockIdx.y;
    __shared__ float pk[32][64];
    __shared__ float vv[32][64];
    int tid = threadIdx.x;
    int mq = tid >> 4, dq = tid & 15;
    float acc[4][4];
#pragma unroll
    for (int i = 0; i < 4; ++i)
#pragma unroll
        for (int j = 0; j < 4; ++j) acc[i][j] = 0.f;
    float zacc = 0.f;
    size_t base = ((size_t)(b * SEQ + c * 256)) * EMB + hh * 64;
    for (int sub = 0; sub < 8; ++sub) {
#pragma unroll
        for (int u = 0; u < 2; ++u) {
            int v4 = tid * 2 + u;           // 0..511 ushort4s
            int r = v4 >> 4, cc = (v4 & 15) << 2;
            size_t g = base + (size_t)(sub * 32 + r) * EMB + cc;
            ushort4 p4 = *(const ushort4*)(PK + g);
            ushort4 q4 = *(const ushort4*)(V + g);
            pk[r][cc + 0] = bf2f(p4.x); pk[r][cc + 1] = bf2f(p4.y);
            pk[r][cc + 2] = bf2f(p4.z); pk[r][cc + 3] = bf2f(p4.w);
            vv[r][cc + 0] = bf2f(q4.x); vv[r][cc + 1] = bf2f(q4.y);
            vv[r][cc + 2] = bf2f(q4.z); vv[r][cc + 3] = bf2f(q4.w);
        }
        __syncthreads();
#pragma unroll 8
        for (int s = 0; s < 32; ++s) {
            float4 aa = *(const float4*)&pk[s][mq * 4];
            float4 bb = *(const float4*)&vv[s][dq * 4];
            float av[4] = { aa.x, aa.y, aa.z, aa.w };
            float bv[4] = { bb.x, bb.y, bb.z, bb.w };
#pragma unroll
            for (int i = 0; i < 4; ++i)
#pragma unroll
                for (int j = 0; j < 4; ++j) acc[i][j] = fmaf(av[i], bv[j], acc[i][j]);
        }
        if (tid < 64) {
            for (int s = 0; s < 32; ++s) zacc += pk[s][tid];
        }
        __syncthreads();
    }
#pragma unroll
    for (int i = 0; i < 4; ++i)
#pragma unroll
        for (int j = 0; j < 4; ++j)
            atomicAdd(&KV[((size_t)bh * 64 + mq * 4 + i) * 64 + dq * 4 + j], acc[i][j]);
    if (tid < 64) atomicAdd(&Z[(size_t)bh * 64 + tid], zacc);
}

// ---------------------------------------------------------------------------
// out[b,s,h,d] = (phi_q[b,s,h,:] . kv[b,h,:,d]) / (phi_q[b,s,h,:] . z[b,h,:])
// grid = (BS_TOK, NH); one wave per block.  PQ/O internal bf16.
// ---------------------------------------------------------------------------
__global__ __launch_bounds__(64) void attn_out(
        const u16* __restrict__ PQ, const float* __restrict__ KV,
        const float* __restrict__ Z, u16* __restrict__ O) {
    int row = blockIdx.x;
    int hh = blockIdx.y;
    int b = row >> 12;                  // / SEQ
    int t = threadIdx.x;
    __shared__ float ph[64];
    float p = bf2f(PQ[(size_t)row * EMB + hh * 64 + t]);
    ph[t] = p;
    int bh = b * NH + hh;
    float d = p * Z[(size_t)bh * 64 + t];
#pragma unroll
    for (int off = 32; off; off >>= 1) d += __shfl_xor(d, off);
    d = fmaxf(d, 1e-20f);               // NaN/zero-denominator guard
    __syncthreads();
    float acc = 0.f;
    const float* kvp = KV + (size_t)bh * 4096 + t;
#pragma unroll 8
    for (int mm = 0; mm < 64; ++mm) acc = fmaf(ph[mm], kvp[mm * 64], acc);
    O[(size_t)row * EMB + hh * 64 + t] = f2bf(acc / d);
}

// ---------------------------------------------------------------------------
extern "C" void kernel_launch(void* const* d_in, const int* in_sizes, int n_in,
                              void* d_out, int out_size, void* d_ws, size_t ws_size,
                              hipStream_t stream) {
    (void)in_sizes; (void)n_in; (void)out_size; (void)ws_size;
    // All reference dtypes are float32 (per setup_inputs) except tokens (int32).
    const int*   tok  = (const int*)d_in[0];
    const float* emb  = (const float*)d_in[1];
    const float* ln1s = (const float*)d_in[2];
    const float* ln1b = (const float*)d_in[3];
    const float* wq   = (const float*)d_in[4];
    const float* wk   = (const float*)d_in[5];
    const float* wv   = (const float*)d_in[6];
    const float* wo   = (const float*)d_in[7];
    const float* ln2s = (const float*)d_in[8];
    const float* ln2b = (const float*)d_in[9];
    const float* w1   = (const float*)d_in[10];
    const float* b1   = (const float*)d_in[11];
    const float* w2   = (const float*)d_in[12];
    const float* b2   = (const float*)d_in[13];
    const float* lnfs = (const float*)d_in[14];
    const float* lnfb = (const float*)d_in[15];

    char* ws = (char*)d_ws;
    const size_t MB = 1024 * 1024;
    // Compact layout, ~97.1 MB total
    float* x = (float*)(ws);                  // [BS,512] f32 residual, 32MB
    u16*   h = (u16*)(ws + 32 * MB);          // [BS,512] bf16, 16MB
    u16*   q = (u16*)(ws + 48 * MB);          // [BS,512] bf16, 16MB
    u16*   k = (u16*)(ws + 64 * MB);          // [BS,512] bf16, 16MB
    u16*   v = (u16*)(ws + 80 * MB);          // [BS,512] bf16, 16MB
    u16*   m = q;                             // [BS,1024] bf16 FFN chunk, aliases q+k (dead)
    float* kv = (float*)(ws + 96 * MB);       // [B,H,64,64] f32 (512KB)
    float* z  = kv + BATCH * NH * HD * HD;    // [B,H,64] (8KB)
    float* maskf = (float*)(ws + 97 * MB);    // [BS] f32 (64KB)

    embed_kernel<<<BS_TOK, 128, 0, stream>>>(tok, emb, x, maskf);

    dim3 g512(EMB / 128, BS_TOK / 128);       // N=512 tiles
    dim3 g1024(1024 / 128, BS_TOK / 128);     // N=1024 tiles (FFN chunk)
    const size_t WSTEP = (size_t)EMB * EMB;

    for (int l = 0; l < NL; ++l) {
        ln_kernel<u16><<<BS_TOK, 256, 0, stream>>>(x, ln1s + l * EMB, ln1b + l * EMB, h);
        // phi_q = relu(q)+eps ; phi_k = (relu(k)+eps)*mask ; v plain
        gemm_kernel<2, u16><<<g512, 256, 0, stream>>>(h, wq + (size_t)l * WSTEP, nullptr, nullptr, nullptr, q, BS_TOK, EMB, EMB, EMB);
        gemm_kernel<2, u16><<<g512, 256, 0, stream>>>(h, wk + (size_t)l * WSTEP, nullptr, maskf,  nullptr, k, BS_TOK, EMB, EMB, EMB);
        gemm_kernel<0, u16><<<g512, 256, 0, stream>>>(h, wv + (size_t)l * WSTEP, nullptr, nullptr, nullptr, v, BS_TOK, EMB, EMB, EMB);

        hipMemsetAsync(kv, 0, (size_t)(BATCH * NH * HD * HD + BATCH * NH * HD) * sizeof(float), stream);
        kv_reduce<<<dim3(BATCH * NH, SEQ / 256), 256, 0, stream>>>(k, v, kv, z);
        attn_out<<<dim3(BS_TOK, NH), 64, 0, stream>>>(q, kv, z, h);

        // x = x + attn_out @ wo
        gemm_kernel<0, float><<<g512, 256, 0, stream>>>(h, wo + (size_t)l * WSTEP, nullptr, nullptr, x, x, BS_TOK, EMB, EMB, EMB);

        ln_kernel<u16><<<BS_TOK, 256, 0, stream>>>(x, ln2s + l * EMB, ln2b + l * EMB, h);
        // FFN in two mid-dim chunks of 1024 to keep workspace small:
        // x += gelu(h @ w1[:,c*1024:+1024] + b1[c]) @ w2[c*1024:+1024,:]  (+b2 on chunk 0)
        const float* w1l = w1 + (size_t)l * EMB * FF;
        const float* w2l = w2 + (size_t)l * FF * EMB;
        const float* b1l = b1 + (size_t)l * FF;
        const float* b2l = b2 + (size_t)l * EMB;
        // chunk 0
        gemm_kernel<1, u16><<<g1024, 256, 0, stream>>>(h, w1l, b1l, nullptr, nullptr, m, BS_TOK, 1024, EMB, FF);
        gemm_kernel<0, float><<<g512, 256, 0, stream>>>(m, w2l, b2l, nullptr, x, x, BS_TOK, EMB, 1024, EMB);
        // chunk 1
        gemm_kernel<1, u16><<<g1024, 256, 0, stream>>>(h, w1l + 1024, b1l + 1024, nullptr, nullptr, m, BS_TOK, 1024, EMB, FF);
        gemm_kernel<0, float><<<g512, 256, 0, stream>>>(m, w2l + (size_t)1024 * EMB, nullptr, nullptr, x, x, BS_TOK, EMB, 1024, EMB);
    }

    ln_kernel<float><<<BS_TOK, 256, 0, stream>>>(x, lnfs, lnfb, (float*)d_out);
}

// Round 5
// 2697.682 us; speedup vs baseline: 3.2022x; 3.2022x over previous
//
#include <hip/hip_runtime.h>
#include <hip/hip_bf16.h>

// Problem shape (fixed by setup_inputs)
#define BATCH 4
#define SEQ   4096
#define BS_TOK (BATCH*SEQ)   // 16384 rows
#define EMB   512
#define NH    8
#define HD    64
#define FF    2048
#define NL    6

typedef unsigned short u16;
typedef __attribute__((ext_vector_type(8))) short bf16x8;   // 8 bf16 = 4 VGPRs
typedef __attribute__((ext_vector_type(4))) float f32x4;

__device__ __forceinline__ float bf2f(u16 u) {
    union { unsigned int i; float f; } x; x.i = ((unsigned int)u) << 16; return x.f;
}
__device__ __forceinline__ u16 f2bf(float f) {
    __hip_bfloat16 b = __float2bfloat16(f);
    return *(u16*)&b;
}

__device__ __forceinline__ float gelu_tanh(float x) {
    float x3 = x * x * x;
    return 0.5f * x * (1.f + tanhf(0.7978845608028654f * (x + 0.044715f * x3)));
}

__device__ __forceinline__ void store_out(float* p, float v) { *p = v; }
__device__ __forceinline__ void store_out(u16* p, float v) { *p = f2bf(v); }

// async global->LDS, 16B per lane; lds dest = wave-uniform base + lane*16
__device__ __forceinline__ void gl_lds16(const void* g, void* l) {
    __builtin_amdgcn_global_load_lds(
        (__attribute__((address_space(1))) void*)g,
        (__attribute__((address_space(3))) void*)l, 16, 0, 0);
}

// ---------------------------------------------------------------------------
// Embedding lookup + sinusoidal positional embedding + padding mask
// ---------------------------------------------------------------------------
__global__ __launch_bounds__(128) void embed_kernel(
        const int* __restrict__ tok, const float* __restrict__ emb,
        float* __restrict__ X, float* __restrict__ maskf) {
    int row = blockIdx.x;
    int t = threadIdx.x;
    int id = tok[row];
    if (t == 0) maskf[row] = (id > 0) ? 1.f : 0.f;
    int s = row & (SEQ - 1);
    int e0 = t * 4;
    float4 u = *(const float4*)(emb + (size_t)id * EMB + e0);
    float vals[4] = { u.x, u.y, u.z, u.w };
    float out[4];
#pragma unroll
    for (int j = 0; j < 4; ++j) {
        int ee = e0 + j;
        int i = ee >> 1;
        float div = expf(-0.035977892078031970f * (float)i);
        float ang = (float)s * div;
        float pe = (ee & 1) ? cosf(ang) : sinf(ang);
        out[j] = vals[j] + pe;
    }
    *(float4*)(X + (size_t)row * EMB + e0) = make_float4(out[0], out[1], out[2], out[3]);
}

// ---------------------------------------------------------------------------
// LayerNorm over E=512; one block (256 thr) per row
// ---------------------------------------------------------------------------
template<typename OUT>
__global__ __launch_bounds__(256) void ln_kernel(
        const float* __restrict__ X, const float* __restrict__ sc,
        const float* __restrict__ bi, OUT* __restrict__ Y) {
    int row = blockIdx.x, t = threadIdx.x;
    const float* x = X + (size_t)row * EMB;
    float a = x[t], b = x[t + 256];
    float s = a + b, q = a * a + b * b;
#pragma unroll
    for (int off = 32; off; off >>= 1) {
        s += __shfl_xor(s, off);
        q += __shfl_xor(q, off);
    }
    __shared__ float ss[4], qq[4];
    int w = t >> 6;
    if ((t & 63) == 0) { ss[w] = s; qq[w] = q; }
    __syncthreads();
    s = ss[0] + ss[1] + ss[2] + ss[3];
    q = qq[0] + qq[1] + qq[2] + qq[3];
    float mu = s * (1.f / 512.f);
    float var = q * (1.f / 512.f) - mu * mu;
    float rstd = rsqrtf(var + 1e-6f);
    float y0 = (a - mu) * rstd * sc[t] + bi[t];
    float y1 = (b - mu) * rstd * sc[t + 256] + bi[t + 256];
    store_out(&Y[(size_t)row * EMB + t], y0);
    store_out(&Y[(size_t)row * EMB + t + 256], y1);
}

// ---------------------------------------------------------------------------
// Weight transpose + bf16 cast: W[K][N] f32  ->  WT[N][K] bf16
// grid (N/32, K/32, z); z selects among 3 sources; dst += z*K*N
// ---------------------------------------------------------------------------
__global__ __launch_bounds__(256) void transpose_w(
        const float* __restrict__ W0, const float* __restrict__ W1,
        const float* __restrict__ W2, u16* __restrict__ WT, int K, int N) {
    const float* W = (blockIdx.z == 0) ? W0 : (blockIdx.z == 1) ? W1 : W2;
    u16* dst = WT + (size_t)blockIdx.z * K * N;
    __shared__ u16 tile[32][33];
    int n0 = blockIdx.x * 32, k0 = blockIdx.y * 32;
    int tx = threadIdx.x & 31, ty = threadIdx.x >> 5;
#pragma unroll
    for (int u = 0; u < 4; ++u)
        tile[ty + u * 8][tx] = f2bf(W[(size_t)(k0 + ty + u * 8) * N + n0 + tx]);
    __syncthreads();
#pragma unroll
    for (int u = 0; u < 4; ++u)
        dst[(size_t)(n0 + ty + u * 8) * K + k0 + tx] = tile[tx][ty + u * 8];
}

// ---------------------------------------------------------------------------
// MFMA bf16 GEMM (m97 structure): C[M,N] = epi(A[M,K]bf16 . BT[N,K]bf16^T)
// 128x128 tile, BK=32, 256 thr = 4 waves (2x2 of 64x64), 4x4 16x16x32 MFMAs.
// OP: 0=none, 1=gelu, 2=relu+1e-3.  epi: (+bias) -> OP -> *rowscale -> +residual
// grid = (N/128, M/128).  lda/ldb in elements.  C ld = N.
// ---------------------------------------------------------------------------
template<int OP, typename OUT>
__global__ __launch_bounds__(256) void mfma_gemm(
        const u16* __restrict__ A, const u16* __restrict__ BT,
        const float* __restrict__ bias, const float* __restrict__ rowscale,
        const float* residual, OUT* C,
        int N, int K, int lda, int ldb) {
    __shared__ u16 As[128 * 32];   // [m][k] contiguous, rows of 32 bf16 (64B)
    __shared__ u16 Bs[128 * 32];   // [n][k]
    int tid = threadIdx.x;
    int wid = tid >> 6, lane = tid & 63;
    int row0 = blockIdx.y * 128, col0 = blockIdx.x * 128;
    int wm = (wid & 1) * 64, wn = (wid >> 1) * 64;
    int quad = lane >> 4, l16 = lane & 15;

    f32x4 acc[4][4];
#pragma unroll
    for (int i = 0; i < 4; ++i)
#pragma unroll
        for (int j = 0; j < 4; ++j)
#pragma unroll
            for (int r = 0; r < 4; ++r) acc[i][j][r] = 0.f;

    // staging: wave wid handles 16-row chunks c = wid*2+u; lane l -> row c*16+l/4,
    // 16B piece (l%4) of the 64B row.  LDS dest = As + c*512 (+ lane*8 u16 by HW).
    const u16* ga[2]; const u16* gb[2]; u16* la[2]; u16* lb[2];
#pragma unroll
    for (int u = 0; u < 2; ++u) {
        int c = wid * 2 + u;
        int r = c * 16 + (lane >> 2);
        int koff = (lane & 3) * 8;
        ga[u] = A  + (size_t)(row0 + r) * lda + koff;
        gb[u] = BT + (size_t)(col0 + r) * ldb + koff;
        la[u] = As + c * 512;
        lb[u] = Bs + c * 512;
    }

    for (int k0 = 0; k0 < K; k0 += 32) {
        gl_lds16(ga[0], la[0]); gl_lds16(ga[1], la[1]);
        gl_lds16(gb[0], lb[0]); gl_lds16(gb[1], lb[1]);
        ga[0] += 32; ga[1] += 32; gb[0] += 32; gb[1] += 32;
        __syncthreads();                       // drains vmcnt -> tiles visible
        bf16x8 af[4], bfv[4];
#pragma unroll
        for (int i = 0; i < 4; ++i)
            af[i] = *(const bf16x8*)(As + (wm + i * 16 + l16) * 32 + quad * 8);
#pragma unroll
        for (int j = 0; j < 4; ++j)
            bfv[j] = *(const bf16x8*)(Bs + (wn + j * 16 + l16) * 32 + quad * 8);
#pragma unroll
        for (int i = 0; i < 4; ++i)
#pragma unroll
            for (int j = 0; j < 4; ++j)
                acc[i][j] = __builtin_amdgcn_mfma_f32_16x16x32_bf16(af[i], bfv[j], acc[i][j], 0, 0, 0);
        __syncthreads();                       // all reads done before re-stage
    }

    // epilogue: D mapping col = lane&15, row = quad*4 + reg  [m89-verified]
    float bc[4];
#pragma unroll
    for (int j = 0; j < 4; ++j)
        bc[j] = bias ? bias[col0 + wn + j * 16 + l16] : 0.f;
#pragma unroll
    for (int i = 0; i < 4; ++i) {
#pragma unroll
        for (int r = 0; r < 4; ++r) {
            int row = row0 + wm + i * 16 + quad * 4 + r;
            float rsv = rowscale ? rowscale[row] : 1.f;
            size_t rb = (size_t)row * N + col0 + wn;
#pragma unroll
            for (int j = 0; j < 4; ++j) {
                float val = acc[i][j][r] + bc[j];
                if (OP == 1) val = gelu_tanh(val);
                if (OP == 2) val = fmaxf(val, 0.f) + 1e-3f;
                val *= rsv;
                size_t idx = rb + j * 16 + l16;
                if (residual) val += residual[idx];
                store_out(&C[idx], val);
            }
        }
    }
}

// ---------------------------------------------------------------------------
// kv[b,h,m,d] = sum_s phi_k[b,s,h,m] * v[b,s,h,d];  z[b,h,m] = sum_s phi_k
// grid = (B*H, SEQ/256); atomics into zeroed buf
// ---------------------------------------------------------------------------
__global__ __launch_bounds__(256) void kv_reduce(
        const u16* __restrict__ PK, const u16* __restrict__ V,
        float* __restrict__ KV, float* __restrict__ Z) {
    int bh = blockIdx.x;
    int b = bh >> 3, hh = bh & 7;
    int c = blockIdx.y;
    __shared__ float pk[32][64];
    __shared__ float vv[32][64];
    int tid = threadIdx.x;
    int mq = tid >> 4, dq = tid & 15;
    float acc[4][4];
#pragma unroll
    for (int i = 0; i < 4; ++i)
#pragma unroll
        for (int j = 0; j < 4; ++j) acc[i][j] = 0.f;
    float zacc = 0.f;
    size_t base = ((size_t)(b * SEQ + c * 256)) * EMB + hh * 64;
    for (int sub = 0; sub < 8; ++sub) {
#pragma unroll
        for (int u = 0; u < 2; ++u) {
            int v4 = tid * 2 + u;
            int r = v4 >> 4, cc = (v4 & 15) << 2;
            size_t g = base + (size_t)(sub * 32 + r) * EMB + cc;
            ushort4 p4 = *(const ushort4*)(PK + g);
            ushort4 q4 = *(const ushort4*)(V + g);
            pk[r][cc + 0] = bf2f(p4.x); pk[r][cc + 1] = bf2f(p4.y);
            pk[r][cc + 2] = bf2f(p4.z); pk[r][cc + 3] = bf2f(p4.w);
            vv[r][cc + 0] = bf2f(q4.x); vv[r][cc + 1] = bf2f(q4.y);
            vv[r][cc + 2] = bf2f(q4.z); vv[r][cc + 3] = bf2f(q4.w);
        }
        __syncthreads();
#pragma unroll 8
        for (int s = 0; s < 32; ++s) {
            float4 aa = *(const float4*)&pk[s][mq * 4];
            float4 bb = *(const float4*)&vv[s][dq * 4];
            float av[4] = { aa.x, aa.y, aa.z, aa.w };
            float bv[4] = { bb.x, bb.y, bb.z, bb.w };
#pragma unroll
            for (int i = 0; i < 4; ++i)
#pragma unroll
                for (int j = 0; j < 4; ++j) acc[i][j] = fmaf(av[i], bv[j], acc[i][j]);
        }
        if (tid < 64) {
            for (int s = 0; s < 32; ++s) zacc += pk[s][tid];
        }
        __syncthreads();
    }
#pragma unroll
    for (int i = 0; i < 4; ++i)
#pragma unroll
        for (int j = 0; j < 4; ++j)
            atomicAdd(&KV[((size_t)bh * 64 + mq * 4 + i) * 64 + dq * 4 + j], acc[i][j]);
    if (tid < 64) atomicAdd(&Z[(size_t)bh * 64 + tid], zacc);
}

// ---------------------------------------------------------------------------
// out[b,s,h,d] = (phi_q . kv[b,h,:,d]) / (phi_q . z[b,h,:])
// grid = (BS/32, NH), 256 thr; kv staged once per 32 rows (16KB LDS)
// ---------------------------------------------------------------------------
__global__ __launch_bounds__(256) void attn_out2(
        const u16* __restrict__ PQ, const float* __restrict__ KV,
        const float* __restrict__ Z, u16* __restrict__ O) {
    __shared__ float kvT[64 * 65];   // [d][m], +1 pad: conflict-free column reads
    __shared__ float zsh[64];
    __shared__ float phs[4][72];
    int hh = blockIdx.y;
    int row0 = blockIdx.x * 32;
    int b = row0 >> 12;
    int bh = b * NH + hh;
    int t = threadIdx.x;
    const float* kvg = KV + (size_t)bh * 4096;
#pragma unroll
    for (int u = 0; u < 16; ++u) {
        int idx = u * 256 + t;                  // m = idx>>6, d = idx&63
        kvT[(idx & 63) * 65 + (idx >> 6)] = kvg[idx];
    }
    if (t < 64) zsh[t] = Z[(size_t)bh * 64 + t];
    __syncthreads();
    int wid = t >> 6, lane = t & 63;
    const float* kvrow = kvT + lane * 65;
    for (int rr = 0; rr < 8; ++rr) {
        int row = row0 + wid * 8 + rr;
        float p = bf2f(PQ[(size_t)row * EMB + hh * 64 + lane]);
        float d = p * zsh[lane];
#pragma unroll
        for (int off = 32; off; off >>= 1) d += __shfl_xor(d, off);
        d = fmaxf(d, 1e-20f);
        phs[wid][lane] = p;
        float acc = 0.f;
#pragma unroll
        for (int mm = 0; mm < 64; ++mm)
            acc = fmaf(phs[wid][mm], kvrow[mm], acc);
        O[(size_t)row * EMB + hh * 64 + lane] = f2bf(acc / d);
    }
}

// ---------------------------------------------------------------------------
extern "C" void kernel_launch(void* const* d_in, const int* in_sizes, int n_in,
                              void* d_out, int out_size, void* d_ws, size_t ws_size,
                              hipStream_t stream) {
    (void)in_sizes; (void)n_in; (void)out_size; (void)ws_size;
    const int*   tok  = (const int*)d_in[0];
    const float* emb  = (const float*)d_in[1];
    const float* ln1s = (const float*)d_in[2];
    const float* ln1b = (const float*)d_in[3];
    const float* wq   = (const float*)d_in[4];
    const float* wk   = (const float*)d_in[5];
    const float* wv   = (const float*)d_in[6];
    const float* wo   = (const float*)d_in[7];
    const float* ln2s = (const float*)d_in[8];
    const float* ln2b = (const float*)d_in[9];
    const float* w1   = (const float*)d_in[10];
    const float* b1   = (const float*)d_in[11];
    const float* w2   = (const float*)d_in[12];
    const float* b2   = (const float*)d_in[13];
    const float* lnfs = (const float*)d_in[14];
    const float* lnfb = (const float*)d_in[15];

    char* ws = (char*)d_ws;
    const size_t MB = 1024 * 1024;
    float* x   = (float*)(ws);                       // [BS,512] f32 residual
    u16*   h   = (u16*)(ws + 32 * MB);               // [BS,512] bf16
    u16*   q   = (u16*)(ws + 48 * MB);               // [BS,512] bf16
    u16*   k   = (u16*)(ws + 64 * MB);               // [BS,512] bf16
    u16*   v   = (u16*)(ws + 80 * MB);               // [BS,512] bf16
    u16*   m   = q;                                  // [BS,1024] FFN chunk (aliases q+k)
    float* kv  = (float*)(ws + 96 * MB);             // [B,H,64,64]
    float* z   = kv + BATCH * NH * HD * HD;          // [B,H,64]
    float* maskf = (float*)(ws + 96 * MB + 768 * 1024);       // [BS]
    u16*   wtA = (u16*)(ws + 97 * MB);               // 3x[512][512] bf16 (1.5MB)
    u16*   wtB = (u16*)(ws + 97 * MB + 1536 * 1024);          // w1T [2048][512] (2MB)
    u16*   wtB2= (u16*)(ws + 97 * MB + (1536 + 2048) * 1024); // w2T [512][2048] (2MB)

    embed_kernel<<<BS_TOK, 128, 0, stream>>>(tok, emb, x, maskf);

    const size_t WSTEP = (size_t)EMB * EMB;
    dim3 gN512(4, 128);    // N=512 MFMA grid
    dim3 gN1024(8, 128);   // N=1024 MFMA grid

    for (int l = 0; l < NL; ++l) {
        ln_kernel<u16><<<BS_TOK, 256, 0, stream>>>(x, ln1s + l * EMB, ln1b + l * EMB, h);
        // bf16-transpose this layer's QKV weights -> wtA (3 x 512x512)
        transpose_w<<<dim3(16, 16, 3), 256, 0, stream>>>(
            wq + l * WSTEP, wk + l * WSTEP, wv + l * WSTEP, wtA, EMB, EMB);
        // phi_q = relu+eps ; phi_k = (relu+eps)*mask ; v plain
        mfma_gemm<2, u16><<<gN512, 256, 0, stream>>>(h, wtA,            nullptr, nullptr, nullptr, q, EMB, EMB, EMB, EMB);
        mfma_gemm<2, u16><<<gN512, 256, 0, stream>>>(h, wtA + WSTEP,    nullptr, maskf,   nullptr, k, EMB, EMB, EMB, EMB);
        mfma_gemm<0, u16><<<gN512, 256, 0, stream>>>(h, wtA + 2 * WSTEP, nullptr, nullptr, nullptr, v, EMB, EMB, EMB, EMB);

        hipMemsetAsync(kv, 0, (size_t)(BATCH * NH * HD * HD + BATCH * NH * HD) * sizeof(float), stream);
        kv_reduce<<<dim3(BATCH * NH, SEQ / 256), 256, 0, stream>>>(k, v, kv, z);
        attn_out2<<<dim3(BS_TOK / 32, NH), 256, 0, stream>>>(q, kv, z, h);

        // x = x + attn_out @ wo   (woT reuses wtA slot 0; wq reads long done)
        transpose_w<<<dim3(16, 16, 1), 256, 0, stream>>>(
            wo + l * WSTEP, wo + l * WSTEP, wo + l * WSTEP, wtA, EMB, EMB);
        mfma_gemm<0, float><<<gN512, 256, 0, stream>>>(h, wtA, nullptr, nullptr, x, x, EMB, EMB, EMB, EMB);

        ln_kernel<u16><<<BS_TOK, 256, 0, stream>>>(x, ln2s + l * EMB, ln2b + l * EMB, h);
        const float* w1l = w1 + (size_t)l * EMB * FF;
        const float* w2l = w2 + (size_t)l * FF * EMB;
        const float* b1l = b1 + (size_t)l * FF;
        const float* b2l = b2 + (size_t)l * EMB;
        transpose_w<<<dim3(64, 16, 1), 256, 0, stream>>>(w1l, w1l, w1l, wtB,  EMB, FF);  // w1T [2048][512]
        transpose_w<<<dim3(16, 64, 1), 256, 0, stream>>>(w2l, w2l, w2l, wtB2, FF, EMB);  // w2T [512][2048]
        // FFN in two 1024-wide mid chunks; m aliases q+k
        for (int c = 0; c < 2; ++c) {
            mfma_gemm<1, u16><<<gN1024, 256, 0, stream>>>(
                h, wtB + (size_t)c * 1024 * EMB, b1l + c * 1024, nullptr, nullptr, m,
                1024, EMB, EMB, EMB);
            mfma_gemm<0, float><<<gN512, 256, 0, stream>>>(
                m, wtB2 + (size_t)c * 1024, (c == 0 ? b2l : nullptr), nullptr, x, x,
                EMB, 1024, 1024, FF);
        }
    }

    ln_kernel<float><<<BS_TOK, 256, 0, stream>>>(x, lnfs, lnfb, (float*)d_out);
}

// Round 6
// 2243.751 us; speedup vs baseline: 3.8501x; 1.2023x over previous
//
#include <hip/hip_runtime.h>
#include <hip/hip_bf16.h>

#define BATCH 4
#define SEQ   4096
#define BS_TOK (BATCH*SEQ)   // 16384 rows
#define EMB   512
#define NH    8
#define HD    64
#define FF    2048
#define NL    6

typedef unsigned short u16;
typedef __attribute__((ext_vector_type(8))) short bf16x8;
typedef __attribute__((ext_vector_type(4))) float f32x4;

__device__ __forceinline__ float bf2f(u16 u) {
    union { unsigned int i; float f; } x; x.i = ((unsigned int)u) << 16; return x.f;
}
__device__ __forceinline__ u16 f2bf(float f) {
    __hip_bfloat16 b = __float2bfloat16(f);
    return *(u16*)&b;
}
__device__ __forceinline__ float gelu_tanh(float x) {
    float x3 = x * x * x;
    return 0.5f * x * (1.f + tanhf(0.7978845608028654f * (x + 0.044715f * x3)));
}
__device__ __forceinline__ void store_out(float* p, float v) { *p = v; }
__device__ __forceinline__ void store_out(u16* p, float v) { *p = f2bf(v); }

__device__ __forceinline__ void gl_lds16(const void* g, void* l) {
    __builtin_amdgcn_global_load_lds(
        (__attribute__((address_space(1))) void*)g,
        (__attribute__((address_space(3))) void*)l, 16, 0, 0);
}

// ---------------------------------------------------------------------------
__global__ __launch_bounds__(128) void embed_kernel(
        const int* __restrict__ tok, const float* __restrict__ emb,
        float* __restrict__ X, float* __restrict__ maskf) {
    int row = blockIdx.x;
    int t = threadIdx.x;
    int id = tok[row];
    if (t == 0) maskf[row] = (id > 0) ? 1.f : 0.f;
    int s = row & (SEQ - 1);
    int e0 = t * 4;
    float4 u = *(const float4*)(emb + (size_t)id * EMB + e0);
    float vals[4] = { u.x, u.y, u.z, u.w };
    float out[4];
#pragma unroll
    for (int j = 0; j < 4; ++j) {
        int ee = e0 + j;
        int i = ee >> 1;
        float div = expf(-0.035977892078031970f * (float)i);
        float ang = (float)s * div;
        float pe = (ee & 1) ? cosf(ang) : sinf(ang);
        out[j] = vals[j] + pe;
    }
    *(float4*)(X + (size_t)row * EMB + e0) = make_float4(out[0], out[1], out[2], out[3]);
}

// ---------------------------------------------------------------------------
template<typename OUT>
__global__ __launch_bounds__(256) void ln_kernel(
        const float* __restrict__ X, const float* __restrict__ sc,
        const float* __restrict__ bi, OUT* __restrict__ Y) {
    int row = blockIdx.x, t = threadIdx.x;
    const float* x = X + (size_t)row * EMB;
    float a = x[t], b = x[t + 256];
    float s = a + b, q = a * a + b * b;
#pragma unroll
    for (int off = 32; off; off >>= 1) {
        s += __shfl_xor(s, off);
        q += __shfl_xor(q, off);
    }
    __shared__ float ss[4], qq[4];
    int w = t >> 6;
    if ((t & 63) == 0) { ss[w] = s; qq[w] = q; }
    __syncthreads();
    s = ss[0] + ss[1] + ss[2] + ss[3];
    q = qq[0] + qq[1] + qq[2] + qq[3];
    float mu = s * (1.f / 512.f);
    float var = q * (1.f / 512.f) - mu * mu;
    float rstd = rsqrtf(var + 1e-6f);
    float y0 = (a - mu) * rstd * sc[t] + bi[t];
    float y1 = (b - mu) * rstd * sc[t + 256] + bi[t + 256];
    store_out(&Y[(size_t)row * EMB + t], y0);
    store_out(&Y[(size_t)row * EMB + t + 256], y1);
}

// ---------------------------------------------------------------------------
// Weight transpose + bf16 cast: W[K][N] f32 -> WT[N][K] bf16; z picks source
// ---------------------------------------------------------------------------
__global__ __launch_bounds__(256) void transpose_w(
        const float* __restrict__ W0, const float* __restrict__ W1,
        const float* __restrict__ W2, const float* __restrict__ W3,
        u16* __restrict__ WT, int K, int N) {
    const float* W = (blockIdx.z == 0) ? W0 : (blockIdx.z == 1) ? W1
                   : (blockIdx.z == 2) ? W2 : W3;
    u16* dst = WT + (size_t)blockIdx.z * K * N;
    __shared__ u16 tile[32][33];
    int n0 = blockIdx.x * 32, k0 = blockIdx.y * 32;
    int tx = threadIdx.x & 31, ty = threadIdx.x >> 5;
#pragma unroll
    for (int u = 0; u < 4; ++u)
        tile[ty + u * 8][tx] = f2bf(W[(size_t)(k0 + ty + u * 8) * N + n0 + tx]);
    __syncthreads();
#pragma unroll
    for (int u = 0; u < 4; ++u)
        dst[(size_t)(n0 + ty + u * 8) * K + k0 + tx] = tile[tx][ty + u * 8];
}

// ---------------------------------------------------------------------------
// MFMA bf16 GEMM: C[M,.] = epi(A[M,K]bf16 . BT[N,K]bf16^T)
// Tile 64(M) x 128(N), BK=64 (two 32-planes), 256 thr = 4 waves of 32x64.
// OP: 0=none, 1=gelu, 3=fused-qkv (seg by col0: q=phi, k=phi*mask, v=none).
// epi: (+bias) -> OP -> (+residual).  grid = (Ntile/128, M/64).
// ---------------------------------------------------------------------------
template<int OP, typename OUT>
__global__ __launch_bounds__(256, 4) void mfma_gemm(
        const u16* __restrict__ A, const u16* __restrict__ BT,
        const float* __restrict__ bias, const float* __restrict__ rowscale,
        const float* residual, OUT* C,
        int K, int lda, int ldb, int ldc) {
    __shared__ u16 As[2 * 64 * 32];    // plane p: [64 rows][32 k] (64B rows)
    __shared__ u16 Bs[2 * 128 * 32];
    int tid = threadIdx.x;
    int wid = tid >> 6, lane = tid & 63;
    int row0 = blockIdx.y * 64, col0 = blockIdx.x * 128;
    int wm = (wid & 1) * 32, wn = (wid >> 1) * 64;
    int quad = lane >> 4, l16 = lane & 15;

    f32x4 acc[2][4];
#pragma unroll
    for (int i = 0; i < 2; ++i)
#pragma unroll
        for (int j = 0; j < 4; ++j)
#pragma unroll
            for (int r = 0; r < 4; ++r) acc[i][j][r] = 0.f;

    // staging: 16-row chunks, lane l -> row chunk*16 + l/4, 16B piece (l&3)
    int rsub = lane >> 2;
    int koff = (lane & 3) * 8;
    const u16* gA  = A  + (size_t)(row0 + wid * 16 + rsub) * lda + koff;
    const u16* gB0 = BT + (size_t)(col0 + (wid * 2 + 0) * 16 + rsub) * ldb + koff;
    const u16* gB1 = BT + (size_t)(col0 + (wid * 2 + 1) * 16 + rsub) * ldb + koff;
    u16* lA  = As + wid * 512;
    u16* lB0 = Bs + (wid * 2 + 0) * 512;
    u16* lB1 = Bs + (wid * 2 + 1) * 512;

    for (int k0 = 0; k0 < K; k0 += 64) {
#pragma unroll
        for (int p = 0; p < 2; ++p) {
            gl_lds16(gA  + p * 32, lA  + p * 2048);
            gl_lds16(gB0 + p * 32, lB0 + p * 4096);
            gl_lds16(gB1 + p * 32, lB1 + p * 4096);
        }
        gA += 64; gB0 += 64; gB1 += 64;
        __syncthreads();
#pragma unroll
        for (int h = 0; h < 2; ++h) {
            bf16x8 af[2], bfv[4];
#pragma unroll
            for (int i = 0; i < 2; ++i)
                af[i] = *(const bf16x8*)(As + h * 2048 + (wm + i * 16 + l16) * 32 + quad * 8);
#pragma unroll
            for (int j = 0; j < 4; ++j)
                bfv[j] = *(const bf16x8*)(Bs + h * 4096 + (wn + j * 16 + l16) * 32 + quad * 8);
#pragma unroll
            for (int i = 0; i < 2; ++i)
#pragma unroll
                for (int j = 0; j < 4; ++j)
                    acc[i][j] = __builtin_amdgcn_mfma_f32_16x16x32_bf16(af[i], bfv[j], acc[i][j], 0, 0, 0);
        }
        __syncthreads();
    }

    // epilogue: D mapping col = lane&15, row = quad*4 + reg (m89-verified)
    int seg = col0 >> 9;   // OP3: 0=q 1=k 2=v
    float bc[4];
#pragma unroll
    for (int j = 0; j < 4; ++j)
        bc[j] = bias ? bias[col0 + wn + j * 16 + l16] : 0.f;
#pragma unroll
    for (int i = 0; i < 2; ++i) {
#pragma unroll
        for (int r = 0; r < 4; ++r) {
            int row = row0 + wm + i * 16 + quad * 4 + r;
            float rsv = (OP == 3 && seg == 1) ? rowscale[row] : 1.f;
            size_t rb = (size_t)row * ldc + col0 + wn;
#pragma unroll
            for (int j = 0; j < 4; ++j) {
                float val = acc[i][j][r] + bc[j];
                if (OP == 1) val = gelu_tanh(val);
                if (OP == 3 && seg < 2) val = fmaxf(val, 0.f) + 1e-3f;
                if (OP == 3 && seg == 1) val *= rsv;
                size_t idx = rb + j * 16 + l16;
                if (residual) val += residual[idx];
                store_out(&C[idx], val);
            }
        }
    }
}

// ---------------------------------------------------------------------------
// kv[b,h,m,d] = sum_s phi_k[s,m]*v[s,d];  z[b,h,m] = sum_s phi_k
// PK/V strided by ld (qkv fused buffer). atomics into zeroed buf.
// ---------------------------------------------------------------------------
__global__ __launch_bounds__(256) void kv_reduce(
        const u16* __restrict__ PK, const u16* __restrict__ V,
        float* __restrict__ KV, float* __restrict__ Z, int ld) {
    int bh = blockIdx.x;
    int b = bh >> 3, hh = bh & 7;
    int c = blockIdx.y;
    __shared__ float pk[32][64];
    __shared__ float vv[32][64];
    int tid = threadIdx.x;
    int mq = tid >> 4, dq = tid & 15;
    float acc[4][4];
#pragma unroll
    for (int i = 0; i < 4; ++i)
#pragma unroll
        for (int j = 0; j < 4; ++j) acc[i][j] = 0.f;
    float zacc = 0.f;
    size_t base = ((size_t)(b * SEQ + c * 256)) * ld + hh * 64;
    for (int sub = 0; sub < 8; ++sub) {
#pragma unroll
        for (int u = 0; u < 2; ++u) {
            int v4 = tid * 2 + u;
            int r = v4 >> 4, cc = (v4 & 15) << 2;
            size_t g = base + (size_t)(sub * 32 + r) * ld + cc;
            ushort4 p4 = *(const ushort4*)(PK + g);
            ushort4 q4 = *(const ushort4*)(V + g);
            pk[r][cc + 0] = bf2f(p4.x); pk[r][cc + 1] = bf2f(p4.y);
            pk[r][cc + 2] = bf2f(p4.z); pk[r][cc + 3] = bf2f(p4.w);
            vv[r][cc + 0] = bf2f(q4.x); vv[r][cc + 1] = bf2f(q4.y);
            vv[r][cc + 2] = bf2f(q4.z); vv[r][cc + 3] = bf2f(q4.w);
        }
        __syncthreads();
#pragma unroll 8
        for (int s = 0; s < 32; ++s) {
            float4 aa = *(const float4*)&pk[s][mq * 4];
            float4 bb = *(const float4*)&vv[s][dq * 4];
            float av[4] = { aa.x, aa.y, aa.z, aa.w };
            float bv[4] = { bb.x, bb.y, bb.z, bb.w };
#pragma unroll
            for (int i = 0; i < 4; ++i)
#pragma unroll
                for (int j = 0; j < 4; ++j) acc[i][j] = fmaf(av[i], bv[j], acc[i][j]);
        }
        if (tid < 64) {
            for (int s = 0; s < 32; ++s) zacc += pk[s][tid];
        }
        __syncthreads();
    }
#pragma unroll
    for (int i = 0; i < 4; ++i)
#pragma unroll
        for (int j = 0; j < 4; ++j)
            atomicAdd(&KV[((size_t)bh * 64 + mq * 4 + i) * 64 + dq * 4 + j], acc[i][j]);
    if (tid < 64) atomicAdd(&Z[(size_t)bh * 64 + tid], zacc);
}

// ---------------------------------------------------------------------------
// out[b,s,h,d] = (phi_q . kv[:,d]) / (phi_q . z);  PQ strided by ld
// ---------------------------------------------------------------------------
__global__ __launch_bounds__(256) void attn_out2(
        const u16* __restrict__ PQ, const float* __restrict__ KV,
        const float* __restrict__ Z, u16* __restrict__ O, int ld) {
    __shared__ float kvT[64 * 65];
    __shared__ float zsh[64];
    __shared__ float phs[4][72];
    int hh = blockIdx.y;
    int row0 = blockIdx.x * 32;
    int b = row0 >> 12;
    int bh = b * NH + hh;
    int t = threadIdx.x;
    const float* kvg = KV + (size_t)bh * 4096;
#pragma unroll
    for (int u = 0; u < 16; ++u) {
        int idx = u * 256 + t;
        kvT[(idx & 63) * 65 + (idx >> 6)] = kvg[idx];
    }
    if (t < 64) zsh[t] = Z[(size_t)bh * 64 + t];
    __syncthreads();
    int wid = t >> 6, lane = t & 63;
    const float* kvrow = kvT + lane * 65;
    for (int rr = 0; rr < 8; ++rr) {
        int row = row0 + wid * 8 + rr;
        float p = bf2f(PQ[(size_t)row * ld + hh * 64 + lane]);
        float d = p * zsh[lane];
#pragma unroll
        for (int off = 32; off; off >>= 1) d += __shfl_xor(d, off);
        d = fmaxf(d, 1e-20f);
        phs[wid][lane] = p;
        float acc = 0.f;
#pragma unroll
        for (int mm = 0; mm < 64; ++mm)
            acc = fmaf(phs[wid][mm], kvrow[mm], acc);
        O[(size_t)row * EMB + hh * 64 + lane] = f2bf(acc / d);
    }
}

// ---------------------------------------------------------------------------
extern "C" void kernel_launch(void* const* d_in, const int* in_sizes, int n_in,
                              void* d_out, int out_size, void* d_ws, size_t ws_size,
                              hipStream_t stream) {
    (void)in_sizes; (void)n_in; (void)out_size; (void)ws_size;
    const int*   tok  = (const int*)d_in[0];
    const float* emb  = (const float*)d_in[1];
    const float* ln1s = (const float*)d_in[2];
    const float* ln1b = (const float*)d_in[3];
    const float* wq   = (const float*)d_in[4];
    const float* wk   = (const float*)d_in[5];
    const float* wv   = (const float*)d_in[6];
    const float* wo   = (const float*)d_in[7];
    const float* ln2s = (const float*)d_in[8];
    const float* ln2b = (const float*)d_in[9];
    const float* w1   = (const float*)d_in[10];
    const float* b1   = (const float*)d_in[11];
    const float* w2   = (const float*)d_in[12];
    const float* b2   = (const float*)d_in[13];
    const float* lnfs = (const float*)d_in[14];
    const float* lnfb = (const float*)d_in[15];

    char* ws = (char*)d_ws;
    const size_t MB = 1024 * 1024;
    float* x    = (float*)(ws);                    // [BS,512] f32 residual, 0-32MB
    u16*   h    = (u16*)(ws + 32 * MB);            // [BS,512] bf16, 32-48
    u16*   qkv  = (u16*)(ws + 48 * MB);            // [BS,1536] bf16, 48-96
    u16*   m    = qkv;                             // [BS,1024] FFN chunk aliases qkv
    float* kv   = (float*)(ws + 96 * MB);          // [B,H,64,64]
    float* z    = kv + BATCH * NH * HD * HD;
    float* maskf = (float*)(ws + 96 * MB + 768 * 1024);   // [BS]
    u16*   wt   = (u16*)(ws + 97 * MB);            // qkvoT: 4x[512][512] (2MB)
    u16*   w1t  = (u16*)(ws + 99 * MB);            // w1T [2048][512] (2MB)
    u16*   w2t  = (u16*)(ws + 101 * MB);           // w2T [512][2048] (2MB)

    embed_kernel<<<BS_TOK, 128, 0, stream>>>(tok, emb, x, maskf);

    const size_t WSTEP = (size_t)EMB * EMB;
    dim3 gQKV(12, BS_TOK / 64);   // N=1536
    dim3 gN512(4, BS_TOK / 64);   // N=512
    dim3 gN1024(8, BS_TOK / 64);  // N=1024

    for (int l = 0; l < NL; ++l) {
        ln_kernel<u16><<<BS_TOK, 256, 0, stream>>>(x, ln1s + l * EMB, ln1b + l * EMB, h);
        // transpose wq,wk,wv,wo -> wt slots 0..3
        transpose_w<<<dim3(16, 16, 4), 256, 0, stream>>>(
            wq + l * WSTEP, wk + l * WSTEP, wv + l * WSTEP, wo + l * WSTEP, wt, EMB, EMB);
        // fused qkv: q=phi, k=phi*mask, v=plain -> qkv [BS,1536]
        mfma_gemm<3, u16><<<gQKV, 256, 0, stream>>>(
            h, wt, nullptr, maskf, nullptr, qkv, EMB, EMB, EMB, 1536);

        hipMemsetAsync(kv, 0, (size_t)(BATCH * NH * HD * HD + BATCH * NH * HD) * sizeof(float), stream);
        kv_reduce<<<dim3(BATCH * NH, SEQ / 256), 256, 0, stream>>>(qkv + 512, qkv + 1024, kv, z, 1536);
        attn_out2<<<dim3(BS_TOK / 32, NH), 256, 0, stream>>>(qkv, kv, z, h, 1536);

        // x = x + attn_out @ wo
        mfma_gemm<0, float><<<gN512, 256, 0, stream>>>(
            h, wt + 3 * WSTEP, nullptr, nullptr, x, x, EMB, EMB, EMB, EMB);

        ln_kernel<u16><<<BS_TOK, 256, 0, stream>>>(x, ln2s + l * EMB, ln2b + l * EMB, h);
        const float* w1l = w1 + (size_t)l * EMB * FF;
        const float* w2l = w2 + (size_t)l * FF * EMB;
        const float* b1l = b1 + (size_t)l * FF;
        const float* b2l = b2 + (size_t)l * EMB;
        transpose_w<<<dim3(64, 16, 1), 256, 0, stream>>>(w1l, w1l, w1l, w1l, w1t, EMB, FF);  // [2048][512]
        transpose_w<<<dim3(16, 64, 1), 256, 0, stream>>>(w2l, w2l, w2l, w2l, w2t, FF, EMB);  // [512][2048]
        for (int c = 0; c < 2; ++c) {
            // m = gelu(h @ w1_chunk + b1_chunk)   [BS,1024]
            mfma_gemm<1, u16><<<gN1024, 256, 0, stream>>>(
                h, w1t + (size_t)c * 1024 * EMB, b1l + c * 1024, nullptr, nullptr, m,
                EMB, EMB, EMB, 1024);
            // x += m @ w2_chunk (+b2 on chunk 0)
            mfma_gemm<0, float><<<gN512, 256, 0, stream>>>(
                m, w2t + (size_t)c * 1024, (c == 0 ? b2l : nullptr), nullptr, x, x,
                1024, 1024, FF, EMB);
        }
    }

    ln_kernel<float><<<BS_TOK, 256, 0, stream>>>(x, lnfs, lnfb, (float*)d_out);
}